// Round 10
// baseline (476.589 us; speedup 1.0000x reference)
//
#include <hip/hip_runtime.h>
#include <stdint.h>

#define N_NODES 100000
#define N_EDGES 1600000
#define N_FEAT 512
#define N_HID 256
#define N_CLASS 40
#define H2SB 64                     // H2 bf16 row stride (shorts): 128 B, line-aligned

typedef float f32x4 __attribute__((ext_vector_type(4)));
typedef __bf16 bf16x8 __attribute__((ext_vector_type(8)));
typedef unsigned short u16x4 __attribute__((ext_vector_type(4)));
typedef unsigned short u16x8 __attribute__((ext_vector_type(8)));

__device__ __forceinline__ unsigned short f2bf(float f) {
  unsigned int u = __float_as_uint(f);
  unsigned int r = (u + 0x7FFFu + ((u >> 16) & 1u)) >> 16;
  return (unsigned short)r;
}
__device__ __forceinline__ float bf2f(unsigned short s) {
  return __uint_as_float(((unsigned int)s) << 16);
}
// packed edge: bits [31:17] = bf16(w) sans sign, [16:0] = col
__device__ __forceinline__ float pk_w(unsigned int p) {
  return __uint_as_float((p >> 17) << 16);
}
__device__ __forceinline__ int pk_c(unsigned int p) { return (int)(p & 0x1FFFFu); }

// ---------------- zero cnt ----------------
__global__ __launch_bounds__(1024) void k_zero(int* __restrict__ cnt) {
  int i = blockIdx.x * 1024 + threadIdx.x;
  if (i < N_NODES) cnt[i] = 0;
}

// ---------------- preamble: W1 transpose+cvt | W2 transpose+cvt | hist(+rank) ------
#define HIST_BLOCKS 1563
#define W1T_BLOCKS  512
#define W2T_BLOCKS  48
__global__ __launch_bounds__(256) void k_pre(const float* __restrict__ W1,
                                             const float* __restrict__ W2,
                                             const int* __restrict__ ei,
                                             unsigned short* __restrict__ W1t,
                                             unsigned short* __restrict__ W2t,
                                             int* __restrict__ cnt,
                                             int* __restrict__ rank) {
  const int bid = blockIdx.x, tid = threadIdx.x;
  if (bid < HIST_BLOCKS) {
    #pragma unroll
    for (int k = 0; k < 4; ++k) {
      int e = bid * 1024 + k * 256 + tid;
      if (e < N_EDGES) rank[e] = atomicAdd(&cnt[ei[e]], 1);
    }
  } else if (bid < HIST_BLOCKS + W1T_BLOCKS) {
    int gid = (bid - HIST_BLOCKS) * 256 + tid;       // W1t[n][k]
    int n = gid >> 9, k = gid & 511;
    W1t[gid] = f2bf(W1[(long)k * N_HID + n]);
  } else {
    int gid = (bid - HIST_BLOCKS - W1T_BLOCKS) * 256 + tid;  // W2t[n][k], n pad 48
    int n = gid >> 8, k = gid & 255;
    W2t[gid] = (n < N_CLASS) ? f2bf(W2[(long)k * N_CLASS + n]) : (unsigned short)0;
  }
}

// ---------------- scan (3 passes) ----------------
__global__ __launch_bounds__(1024) void k_scan_a(const int* __restrict__ cnt,
                                                 int* __restrict__ rp,
                                                 int* __restrict__ bsum) {
  __shared__ int sm[1024];
  const int tid = threadIdx.x;
  const int i = blockIdx.x * 1024 + tid;
  int v = (i < N_NODES) ? cnt[i] : 0;
  sm[tid] = v;
  __syncthreads();
  #pragma unroll
  for (int d = 1; d < 1024; d <<= 1) {
    int t = (tid >= d) ? sm[tid - d] : 0;
    __syncthreads();
    sm[tid] += t;
    __syncthreads();
  }
  if (i < N_NODES) rp[i] = sm[tid] - v;
  if (tid == 1023) bsum[blockIdx.x] = sm[1023];
}

__global__ __launch_bounds__(128) void k_scan_b(const int* __restrict__ bsum,
                                                int* __restrict__ boffs,
                                                int* __restrict__ rp) {
  __shared__ int sm[128];
  const int tid = threadIdx.x;
  const int nb = (N_NODES + 1023) >> 10;
  int v = (tid < nb) ? bsum[tid] : 0;
  sm[tid] = v;
  __syncthreads();
  #pragma unroll
  for (int d = 1; d < 128; d <<= 1) {
    int t = (tid >= d) ? sm[tid - d] : 0;
    __syncthreads();
    sm[tid] += t;
    __syncthreads();
  }
  boffs[tid] = sm[tid] - v;
  if (tid == 127) rp[N_NODES] = sm[127];
}

__global__ void k_scan_c(int* __restrict__ rp, const int* __restrict__ boffs) {
  int i = blockIdx.x * 256 + threadIdx.x;
  if (i >= N_NODES) return;
  rp[i] += boffs[i >> 10];
}

// ---------------- fused: GEMM1 (B-resident LDS, nt X loads) + scatter ----------------
// blocks [0,250): gemm role (125 row-ranges x 2 col-panels); [250, 250+782): scatter.
#define GEMM_BLOCKS 250
#define SCAT_BLOCKS 782             // ceil(1.6e6 / 2048)
__global__ __launch_bounds__(1024) void k_fused1(const float* __restrict__ X,
                                                 const unsigned short* __restrict__ W1t,
                                                 const float* __restrict__ b1,
                                                 unsigned short* __restrict__ H1,
                                                 const int* __restrict__ ei,
                                                 const float* __restrict__ ew,
                                                 const int* __restrict__ rank,
                                                 const int* __restrict__ rp,
                                                 unsigned int* __restrict__ cwp) {
  __shared__ __align__(16) unsigned short Bs[128 * 512];   // 128 KB
  const int t = threadIdx.x;

  if (blockIdx.x >= GEMM_BLOCKS) {         // ---- scatter role ----
    int sb = blockIdx.x - GEMM_BLOCKS;
    #pragma unroll
    for (int k = 0; k < 2; ++k) {
      int e = sb * 2048 + k * 1024 + t;
      if (e < N_EDGES) {
        int r = ei[e];
        int pos = rp[r] + rank[e];
        unsigned int w15 = (unsigned int)f2bf(ew[e]);      // sign always 0
        cwp[pos] = (w15 << 17) | (unsigned int)ei[N_EDGES + e];
      }
    }
    return;
  }

  // ---- gemm role ----
  const int pair = blockIdx.x >> 1, panel = blockIdx.x & 1;
  const long rb = (long)pair * 800;
  const int n0 = panel * 128;

  {
    const int col = t >> 3, seg = t & 7;
    const unsigned short* src = W1t + (long)(n0 + col) * N_FEAT;
    #pragma unroll
    for (int j = 0; j < 8; ++j) {
      int slot = seg * 8 + j;
      int ps = slot ^ (col & 7);
      *(u16x8*)&Bs[col * 512 + ps * 8] = *(const u16x8*)(src + slot * 8);
    }
  }
  __syncthreads();

  const int lane = t & 63;
  const int wid = t >> 6;                  // 0..15
  const int lr = lane & 15;
  const int lkg = lane >> 4;               // 0..3

  for (int c = wid; c < 50; c += 16) {
    const long row0 = rb + c * 16;
    const float* ap = X + (row0 + lr) * N_FEAT + lkg * 8;
    f32x4 acc[8] = {};

    #pragma unroll 2
    for (int k0 = 0; k0 < N_FEAT; k0 += 32) {
      f32x4 xa = __builtin_nontemporal_load((const f32x4*)(ap + k0));
      f32x4 xb = __builtin_nontemporal_load((const f32x4*)(ap + k0 + 4));
      bf16x8 av;
      av[0] = (__bf16)xa[0]; av[1] = (__bf16)xa[1];
      av[2] = (__bf16)xa[2]; av[3] = (__bf16)xa[3];
      av[4] = (__bf16)xb[0]; av[5] = (__bf16)xb[1];
      av[6] = (__bf16)xb[2]; av[7] = (__bf16)xb[3];
      const int slot = (k0 >> 3) + lkg;
      const int ps = slot ^ (lr & 7);
      #pragma unroll
      for (int nt = 0; nt < 8; ++nt) {
        bf16x8 bv = *(const bf16x8*)&Bs[(nt * 16 + lr) * 512 + ps * 8];
        acc[nt] = __builtin_amdgcn_mfma_f32_16x16x32_bf16(av, bv, acc[nt], 0, 0, 0);
      }
    }

    #pragma unroll
    for (int nt = 0; nt < 8; ++nt) {
      int colg = n0 + nt * 16 + lr;
      float bias = b1[colg];
      #pragma unroll
      for (int i = 0; i < 4; ++i) {
        long row = row0 + lkg * 4 + i;
        H1[row * N_HID + colg] = f2bf(acc[nt][i] + bias);
      }
    }
  }
}

// ---------------- SPMM1 + relu: H1r = bf16(relu(A @ H1)), 8-deep gather ----------
__global__ __launch_bounds__(256) void k_spmm1(const int* __restrict__ row_ptr,
                                               const unsigned int* __restrict__ cwp,
                                               const unsigned short* __restrict__ H1,
                                               unsigned short* __restrict__ H1r) {
  int r = blockIdx.x * 4 + (threadIdx.x >> 6);
  int lane = threadIdx.x & 63;
  if (r >= N_NODES) return;
  int s = row_ptr[r], e = row_ptr[r + 1];
  float a0 = 0.f, a1 = 0.f, a2 = 0.f, a3 = 0.f;
  const unsigned short* Hb = H1 + lane * 4;
  int i = s;
  for (; i + 8 <= e; i += 8) {
    uint4 q0 = *(const uint4*)(cwp + i);
    uint4 q1 = *(const uint4*)(cwp + i + 4);
    unsigned int cc[8] = {q0.x, q0.y, q0.z, q0.w, q1.x, q1.y, q1.z, q1.w};
    u16x4 h[8];
    #pragma unroll
    for (int j = 0; j < 8; ++j)
      h[j] = *(const u16x4*)(Hb + (long)pk_c(cc[j]) * N_HID);
    #pragma unroll
    for (int j = 0; j < 8; ++j) {
      float w = pk_w(cc[j]);
      a0 += w * bf2f(h[j][0]);
      a1 += w * bf2f(h[j][1]);
      a2 += w * bf2f(h[j][2]);
      a3 += w * bf2f(h[j][3]);
    }
  }
  for (; i < e; ++i) {
    unsigned int p = cwp[i];
    float w = pk_w(p);
    u16x4 hv = *(const u16x4*)(Hb + (long)pk_c(p) * N_HID);
    a0 += w * bf2f(hv[0]);
    a1 += w * bf2f(hv[1]);
    a2 += w * bf2f(hv[2]);
    a3 += w * bf2f(hv[3]);
  }
  u16x4 o;
  o[0] = f2bf(fmaxf(a0, 0.f));
  o[1] = f2bf(fmaxf(a1, 0.f));
  o[2] = f2bf(fmaxf(a2, 0.f));
  o[3] = f2bf(fmaxf(a3, 0.f));
  *(u16x4*)(H1r + (long)r * N_HID + lane * 4) = o;
}

// ---------------- GEMM2 direct-from-global: H2(bf16)[.][64] = H1r @ W2 + b2 --------
__global__ __launch_bounds__(256) void k_gemm2(const unsigned short* __restrict__ H1r,
                                               const unsigned short* __restrict__ W2t,
                                               const float* __restrict__ b2,
                                               unsigned short* __restrict__ H2) {
  const int t = threadIdx.x;
  const int lane = t & 63;
  const int wid = t >> 6;
  const long m0 = (long)blockIdx.x * 128;
  const int lr = lane & 15;
  const int lk = (lane >> 4) * 8;

  const unsigned short* Ab[2];
  #pragma unroll
  for (int mt = 0; mt < 2; ++mt) {
    long r = m0 + wid * 32 + mt * 16 + lr;
    if (r >= N_NODES) r = N_NODES - 1;
    Ab[mt] = H1r + r * N_HID + lk;
  }
  const unsigned short* Bb[3];
  #pragma unroll
  for (int nt = 0; nt < 3; ++nt)
    Bb[nt] = W2t + (long)(nt * 16 + lr) * N_HID + lk;

  f32x4 acc[2][3] = {};
  #pragma unroll
  for (int k0 = 0; k0 < N_HID; k0 += 32) {
    bf16x8 av[2], bvv[3];
    #pragma unroll
    for (int mt = 0; mt < 2; ++mt) av[mt] = *(const bf16x8*)(Ab[mt] + k0);
    #pragma unroll
    for (int nt = 0; nt < 3; ++nt) bvv[nt] = *(const bf16x8*)(Bb[nt] + k0);
    #pragma unroll
    for (int mt = 0; mt < 2; ++mt)
      #pragma unroll
      for (int nt = 0; nt < 3; ++nt)
        acc[mt][nt] = __builtin_amdgcn_mfma_f32_16x16x32_bf16(av[mt], bvv[nt], acc[mt][nt], 0, 0, 0);
  }

  #pragma unroll
  for (int nt = 0; nt < 3; ++nt) {
    int col = nt * 16 + lr;
    if (col < N_CLASS) {
      float bias = b2[col];
      #pragma unroll
      for (int mt = 0; mt < 2; ++mt) {
        #pragma unroll
        for (int i = 0; i < 4; ++i) {
          long row = m0 + wid * 32 + mt * 16 + (lane >> 4) * 4 + i;
          if (row < N_NODES) H2[row * H2SB + col] = f2bf(acc[mt][nt][i] + bias);
        }
      }
    }
  }
}

// ---------------- SPMM2 + log_softmax fused, 8-deep, bf16 H2 ----------------
__global__ __launch_bounds__(256) void k_spmm2_lsm(const int* __restrict__ row_ptr,
                                                   const unsigned int* __restrict__ cwp,
                                                   const unsigned short* __restrict__ H2,
                                                   float* __restrict__ out) {
  int r = blockIdx.x * 4 + (threadIdx.x >> 6);
  int lane = threadIdx.x & 63;
  if (r >= N_NODES) return;
  int s = row_ptr[r], e = row_ptr[r + 1];
  float acc = 0.f;
  const bool act = lane < N_CLASS;
  int i = s;
  for (; i + 8 <= e; i += 8) {
    uint4 q0 = *(const uint4*)(cwp + i);
    uint4 q1 = *(const uint4*)(cwp + i + 4);
    unsigned int cc[8] = {q0.x, q0.y, q0.z, q0.w, q1.x, q1.y, q1.z, q1.w};
    float h[8];
    #pragma unroll
    for (int j = 0; j < 8; ++j)
      h[j] = act ? bf2f(H2[(long)pk_c(cc[j]) * H2SB + lane]) : 0.f;
    #pragma unroll
    for (int j = 0; j < 8; ++j) acc += pk_w(cc[j]) * h[j];
  }
  for (; i < e; ++i) {
    unsigned int p = cwp[i];
    if (act) acc += pk_w(p) * bf2f(H2[(long)pk_c(p) * H2SB + lane]);
  }
  float v = act ? acc : -INFINITY;
  float m = v;
  #pragma unroll
  for (int d = 32; d > 0; d >>= 1) m = fmaxf(m, __shfl_xor(m, d));
  float ex = act ? __expf(v - m) : 0.f;
  float ssum = ex;
  #pragma unroll
  for (int d = 32; d > 0; d >>= 1) ssum += __shfl_xor(ssum, d);
  float ls = __logf(ssum);
  if (act) out[(long)r * N_CLASS + lane] = v - m - ls;
}

extern "C" void kernel_launch(void* const* d_in, const int* in_sizes, int n_in,
                              void* d_out, int out_size, void* d_ws, size_t ws_size,
                              hipStream_t stream) {
  (void)in_sizes; (void)n_in; (void)out_size; (void)ws_size;
  const float* X  = (const float*)d_in[0];
  const int*   EI = (const int*)d_in[1];
  const float* EW = (const float*)d_in[2];
  const float* W1 = (const float*)d_in[3];
  const float* b1 = (const float*)d_in[4];
  const float* W2 = (const float*)d_in[5];
  const float* b2 = (const float*)d_in[6];
  float* out = (float*)d_out;

  char* p = (char*)d_ws;
  auto take = [&](size_t bytes) {
    char* r = p;
    p += (bytes + 511) & ~(size_t)511;
    return r;
  };
  unsigned short* W1t   = (unsigned short*)take((size_t)N_HID * N_FEAT * 2);
  unsigned short* W2t   = (unsigned short*)take((size_t)48 * N_HID * 2);
  int*            cnt   = (int*)take((size_t)N_NODES * 4);
  int*            rp    = (int*)take((size_t)(N_NODES + 1) * 4);
  int*            bsum  = (int*)take((size_t)128 * 4);
  int*            boffs = (int*)take((size_t)128 * 4);
  int*            rank  = (int*)take((size_t)N_EDGES * 4);
  unsigned int*   cwp   = (unsigned int*)take((size_t)N_EDGES * 4);
  unsigned short* H1    = (unsigned short*)take((size_t)N_NODES * N_HID * 2);
  unsigned short* H1r   = (unsigned short*)take((size_t)N_NODES * N_HID * 2);
  unsigned short* H2    = (unsigned short*)take((size_t)N_NODES * H2SB * 2);

  const int NB_SCAN = (N_NODES + 1023) / 1024;

  k_zero<<<NB_SCAN, 1024, 0, stream>>>(cnt);
  k_pre<<<HIST_BLOCKS + W1T_BLOCKS + W2T_BLOCKS, 256, 0, stream>>>(W1, W2, EI, W1t, W2t, cnt, rank);
  k_scan_a<<<NB_SCAN, 1024, 0, stream>>>(cnt, rp, bsum);
  k_scan_b<<<1, 128, 0, stream>>>(bsum, boffs, rp);
  k_scan_c<<<(N_NODES + 255) / 256, 256, 0, stream>>>(rp, boffs);
  k_fused1<<<GEMM_BLOCKS + SCAT_BLOCKS, 1024, 0, stream>>>(X, W1t, b1, H1, EI, EW, rank, rp, cwp);
  k_spmm1<<<(N_NODES + 3) / 4, 256, 0, stream>>>(rp, cwp, H1, H1r);
  k_gemm2<<<(N_NODES + 127) / 128, 256, 0, stream>>>(H1r, W2t, b2, H2);
  k_spmm2_lsm<<<(N_NODES + 3) / 4, 256, 0, stream>>>(rp, cwp, H2, out);
}

// Round 11
// 472.645 us; speedup vs baseline: 1.0083x; 1.0083x over previous
//
#include <hip/hip_runtime.h>
#include <stdint.h>

#define N_NODES 100000
#define N_EDGES 1600000
#define N_FEAT 512
#define N_HID 256
#define N_CLASS 40
#define H2S 48                      // padded H2 row stride (floats)

typedef float f32x4 __attribute__((ext_vector_type(4)));
typedef __bf16 bf16x8 __attribute__((ext_vector_type(8)));
typedef unsigned short u16x4 __attribute__((ext_vector_type(4)));
typedef unsigned short u16x8 __attribute__((ext_vector_type(8)));

__device__ __forceinline__ unsigned short f2bf(float f) {
  unsigned int u = __float_as_uint(f);
  unsigned int r = (u + 0x7FFFu + ((u >> 16) & 1u)) >> 16;
  return (unsigned short)r;
}
__device__ __forceinline__ float bf2f(unsigned short s) {
  return __uint_as_float(((unsigned int)s) << 16);
}
// packed edge: bits [31:17] = bf16(w) sans sign, [16:0] = col
__device__ __forceinline__ float pk_w(unsigned int p) {
  return __uint_as_float((p >> 17) << 16);
}
__device__ __forceinline__ int pk_c(unsigned int p) { return (int)(p & 0x1FFFFu); }

// ---------------- zero cnt (rocclr fill was 118 us for 400 KB) ----------------
__global__ __launch_bounds__(1024) void k_zero(int* __restrict__ cnt) {
  int i = blockIdx.x * 1024 + threadIdx.x;
  if (i < N_NODES) cnt[i] = 0;
}

// ---------------- preamble: W1 transpose+cvt | W2 transpose+cvt | hist(+rank) ------
#define HIST_BLOCKS 1563
#define W1T_BLOCKS  512
#define W2T_BLOCKS  48
__global__ __launch_bounds__(256) void k_pre(const float* __restrict__ W1,
                                             const float* __restrict__ W2,
                                             const int* __restrict__ ei,
                                             unsigned short* __restrict__ W1t,
                                             unsigned short* __restrict__ W2t,
                                             int* __restrict__ cnt,
                                             int* __restrict__ rank) {
  const int bid = blockIdx.x, tid = threadIdx.x;
  if (bid < HIST_BLOCKS) {
    #pragma unroll
    for (int k = 0; k < 4; ++k) {
      int e = bid * 1024 + k * 256 + tid;
      if (e < N_EDGES) rank[e] = atomicAdd(&cnt[ei[e]], 1);
    }
  } else if (bid < HIST_BLOCKS + W1T_BLOCKS) {
    int gid = (bid - HIST_BLOCKS) * 256 + tid;       // W1t[n][k]
    int n = gid >> 9, k = gid & 511;
    W1t[gid] = f2bf(W1[(long)k * N_HID + n]);
  } else {
    int gid = (bid - HIST_BLOCKS - W1T_BLOCKS) * 256 + tid;  // W2t[n][k], n pad 48
    int n = gid >> 8, k = gid & 255;
    W2t[gid] = (n < N_CLASS) ? f2bf(W2[(long)k * N_CLASS + n]) : (unsigned short)0;
  }
}

// ---------------- scan (3 passes) ----------------
__global__ __launch_bounds__(1024) void k_scan_a(const int* __restrict__ cnt,
                                                 int* __restrict__ rp,
                                                 int* __restrict__ bsum) {
  __shared__ int sm[1024];
  const int tid = threadIdx.x;
  const int i = blockIdx.x * 1024 + tid;
  int v = (i < N_NODES) ? cnt[i] : 0;
  sm[tid] = v;
  __syncthreads();
  #pragma unroll
  for (int d = 1; d < 1024; d <<= 1) {
    int t = (tid >= d) ? sm[tid - d] : 0;
    __syncthreads();
    sm[tid] += t;
    __syncthreads();
  }
  if (i < N_NODES) rp[i] = sm[tid] - v;
  if (tid == 1023) bsum[blockIdx.x] = sm[1023];
}

__global__ __launch_bounds__(128) void k_scan_b(const int* __restrict__ bsum,
                                                int* __restrict__ boffs,
                                                int* __restrict__ rp) {
  __shared__ int sm[128];
  const int tid = threadIdx.x;
  const int nb = (N_NODES + 1023) >> 10;
  int v = (tid < nb) ? bsum[tid] : 0;
  sm[tid] = v;
  __syncthreads();
  #pragma unroll
  for (int d = 1; d < 128; d <<= 1) {
    int t = (tid >= d) ? sm[tid - d] : 0;
    __syncthreads();
    sm[tid] += t;
    __syncthreads();
  }
  boffs[tid] = sm[tid] - v;
  if (tid == 127) rp[N_NODES] = sm[127];
}

__global__ void k_scan_c(int* __restrict__ rp, const int* __restrict__ boffs) {
  int i = blockIdx.x * 256 + threadIdx.x;
  if (i >= N_NODES) return;
  rp[i] += boffs[i >> 10];
}

// ---------------- scatter: packed 4B records, no atomics ----------------
__global__ __launch_bounds__(512) void k_scatter(const int* __restrict__ ei,
                                                 const float* __restrict__ ew,
                                                 const int* __restrict__ rank,
                                                 const int* __restrict__ rp,
                                                 unsigned int* __restrict__ cwp) {
  const int t = threadIdx.x;
  #pragma unroll
  for (int k = 0; k < 4; ++k) {
    int e = blockIdx.x * 2048 + k * 512 + t;
    if (e < N_EDGES) {
      int r = ei[e];
      int pos = rp[r] + rank[e];
      unsigned int w15 = (unsigned int)f2bf(ew[e]);      // sign always 0
      cwp[pos] = (w15 << 17) | (unsigned int)ei[N_EDGES + e];
    }
  }
}

// ---------------- GEMM1 v2: B-resident LDS, barrier-free M-streaming, nt X loads ----
__global__ __launch_bounds__(1024) void k_gemm1(const float* __restrict__ X,
                                                const unsigned short* __restrict__ W1t,
                                                const float* __restrict__ b1,
                                                unsigned short* __restrict__ H1) {
  __shared__ __align__(16) unsigned short Bs[128 * 512];   // 128 KB
  const int t = threadIdx.x;
  const int pair = blockIdx.x >> 1, panel = blockIdx.x & 1;
  const long rb = (long)pair * 800;
  const int n0 = panel * 128;

  {
    const int col = t >> 3, seg = t & 7;
    const unsigned short* src = W1t + (long)(n0 + col) * N_FEAT;
    #pragma unroll
    for (int j = 0; j < 8; ++j) {
      int slot = seg * 8 + j;
      int ps = slot ^ (col & 7);
      *(u16x8*)&Bs[col * 512 + ps * 8] = *(const u16x8*)(src + slot * 8);
    }
  }
  __syncthreads();

  const int lane = t & 63;
  const int wid = t >> 6;                  // 0..15
  const int lr = lane & 15;
  const int lkg = lane >> 4;               // 0..3

  for (int c = wid; c < 50; c += 16) {
    const long row0 = rb + c * 16;
    const float* ap = X + (row0 + lr) * N_FEAT + lkg * 8;
    f32x4 acc[8] = {};

    #pragma unroll 2
    for (int k0 = 0; k0 < N_FEAT; k0 += 32) {
      f32x4 xa = __builtin_nontemporal_load((const f32x4*)(ap + k0));
      f32x4 xb = __builtin_nontemporal_load((const f32x4*)(ap + k0 + 4));
      bf16x8 av;
      av[0] = (__bf16)xa[0]; av[1] = (__bf16)xa[1];
      av[2] = (__bf16)xa[2]; av[3] = (__bf16)xa[3];
      av[4] = (__bf16)xb[0]; av[5] = (__bf16)xb[1];
      av[6] = (__bf16)xb[2]; av[7] = (__bf16)xb[3];
      const int slot = (k0 >> 3) + lkg;
      const int ps = slot ^ (lr & 7);
      #pragma unroll
      for (int nt = 0; nt < 8; ++nt) {
        bf16x8 bv = *(const bf16x8*)&Bs[(nt * 16 + lr) * 512 + ps * 8];
        acc[nt] = __builtin_amdgcn_mfma_f32_16x16x32_bf16(av, bv, acc[nt], 0, 0, 0);
      }
    }

    #pragma unroll
    for (int nt = 0; nt < 8; ++nt) {
      int colg = n0 + nt * 16 + lr;
      float bias = b1[colg];
      #pragma unroll
      for (int i = 0; i < 4; ++i) {
        long row = row0 + lkg * 4 + i;
        H1[row * N_HID + colg] = f2bf(acc[nt][i] + bias);
      }
    }
  }
}

// ---------------- SPMM1 + relu: H1r = bf16(relu(A @ H1)), 8-deep gather ----------
__global__ __launch_bounds__(256) void k_spmm1(const int* __restrict__ row_ptr,
                                               const unsigned int* __restrict__ cwp,
                                               const unsigned short* __restrict__ H1,
                                               unsigned short* __restrict__ H1r) {
  int r = blockIdx.x * 4 + (threadIdx.x >> 6);
  int lane = threadIdx.x & 63;
  if (r >= N_NODES) return;
  int s = row_ptr[r], e = row_ptr[r + 1];
  float a0 = 0.f, a1 = 0.f, a2 = 0.f, a3 = 0.f;
  const unsigned short* Hb = H1 + lane * 4;
  int i = s;
  for (; i + 8 <= e; i += 8) {
    uint4 q0 = *(const uint4*)(cwp + i);
    uint4 q1 = *(const uint4*)(cwp + i + 4);
    unsigned int cc[8] = {q0.x, q0.y, q0.z, q0.w, q1.x, q1.y, q1.z, q1.w};
    u16x4 h[8];
    #pragma unroll
    for (int j = 0; j < 8; ++j)
      h[j] = *(const u16x4*)(Hb + (long)pk_c(cc[j]) * N_HID);
    #pragma unroll
    for (int j = 0; j < 8; ++j) {
      float w = pk_w(cc[j]);
      a0 += w * bf2f(h[j][0]);
      a1 += w * bf2f(h[j][1]);
      a2 += w * bf2f(h[j][2]);
      a3 += w * bf2f(h[j][3]);
    }
  }
  for (; i < e; ++i) {
    unsigned int p = cwp[i];
    float w = pk_w(p);
    u16x4 hv = *(const u16x4*)(Hb + (long)pk_c(p) * N_HID);
    a0 += w * bf2f(hv[0]);
    a1 += w * bf2f(hv[1]);
    a2 += w * bf2f(hv[2]);
    a3 += w * bf2f(hv[3]);
  }
  u16x4 o;
  o[0] = f2bf(fmaxf(a0, 0.f));
  o[1] = f2bf(fmaxf(a1, 0.f));
  o[2] = f2bf(fmaxf(a2, 0.f));
  o[3] = f2bf(fmaxf(a3, 0.f));
  *(u16x4*)(H1r + (long)r * N_HID + lane * 4) = o;
}

// ---------------- GEMM2 direct-from-global: H2[.][48] = H1r @ W2 + b2 -------------
__global__ __launch_bounds__(256) void k_gemm2(const unsigned short* __restrict__ H1r,
                                               const unsigned short* __restrict__ W2t,
                                               const float* __restrict__ b2,
                                               float* __restrict__ H2) {
  const int t = threadIdx.x;
  const int lane = t & 63;
  const int wid = t >> 6;
  const long m0 = (long)blockIdx.x * 128;
  const int lr = lane & 15;
  const int lk = (lane >> 4) * 8;

  const unsigned short* Ab[2];
  #pragma unroll
  for (int mt = 0; mt < 2; ++mt) {
    long r = m0 + wid * 32 + mt * 16 + lr;
    if (r >= N_NODES) r = N_NODES - 1;
    Ab[mt] = H1r + r * N_HID + lk;
  }
  const unsigned short* Bb[3];
  #pragma unroll
  for (int nt = 0; nt < 3; ++nt)
    Bb[nt] = W2t + (long)(nt * 16 + lr) * N_HID + lk;

  f32x4 acc[2][3] = {};
  #pragma unroll
  for (int k0 = 0; k0 < N_HID; k0 += 32) {
    bf16x8 av[2], bvv[3];
    #pragma unroll
    for (int mt = 0; mt < 2; ++mt) av[mt] = *(const bf16x8*)(Ab[mt] + k0);
    #pragma unroll
    for (int nt = 0; nt < 3; ++nt) bvv[nt] = *(const bf16x8*)(Bb[nt] + k0);
    #pragma unroll
    for (int mt = 0; mt < 2; ++mt)
      #pragma unroll
      for (int nt = 0; nt < 3; ++nt)
        acc[mt][nt] = __builtin_amdgcn_mfma_f32_16x16x32_bf16(av[mt], bvv[nt], acc[mt][nt], 0, 0, 0);
  }

  #pragma unroll
  for (int nt = 0; nt < 3; ++nt) {
    int col = nt * 16 + lr;
    if (col < N_CLASS) {
      float bias = b2[col];
      #pragma unroll
      for (int mt = 0; mt < 2; ++mt) {
        #pragma unroll
        for (int i = 0; i < 4; ++i) {
          long row = m0 + wid * 32 + mt * 16 + (lane >> 4) * 4 + i;
          if (row < N_NODES) H2[row * H2S + col] = acc[mt][nt][i] + bias;
        }
      }
    }
  }
}

// ---------------- SPMM2 + log_softmax fused, 8-deep, packed edges ----------------
__global__ __launch_bounds__(256) void k_spmm2_lsm(const int* __restrict__ row_ptr,
                                                   const unsigned int* __restrict__ cwp,
                                                   const float* __restrict__ H2,
                                                   float* __restrict__ out) {
  int r = blockIdx.x * 4 + (threadIdx.x >> 6);
  int lane = threadIdx.x & 63;
  if (r >= N_NODES) return;
  int s = row_ptr[r], e = row_ptr[r + 1];
  float acc = 0.f;
  const bool act = lane < N_CLASS;
  int i = s;
  for (; i + 8 <= e; i += 8) {
    uint4 q0 = *(const uint4*)(cwp + i);
    uint4 q1 = *(const uint4*)(cwp + i + 4);
    unsigned int cc[8] = {q0.x, q0.y, q0.z, q0.w, q1.x, q1.y, q1.z, q1.w};
    float h[8];
    #pragma unroll
    for (int j = 0; j < 8; ++j)
      h[j] = act ? H2[(long)pk_c(cc[j]) * H2S + lane] : 0.f;
    #pragma unroll
    for (int j = 0; j < 8; ++j) acc += pk_w(cc[j]) * h[j];
  }
  for (; i < e; ++i) {
    unsigned int p = cwp[i];
    if (act) acc += pk_w(p) * H2[(long)pk_c(p) * H2S + lane];
  }
  float v = act ? acc : -INFINITY;
  float m = v;
  #pragma unroll
  for (int d = 32; d > 0; d >>= 1) m = fmaxf(m, __shfl_xor(m, d));
  float ex = act ? __expf(v - m) : 0.f;
  float ssum = ex;
  #pragma unroll
  for (int d = 32; d > 0; d >>= 1) ssum += __shfl_xor(ssum, d);
  float ls = __logf(ssum);
  if (act) out[(long)r * N_CLASS + lane] = v - m - ls;
}

extern "C" void kernel_launch(void* const* d_in, const int* in_sizes, int n_in,
                              void* d_out, int out_size, void* d_ws, size_t ws_size,
                              hipStream_t stream) {
  (void)in_sizes; (void)n_in; (void)out_size; (void)ws_size;
  const float* X  = (const float*)d_in[0];
  const int*   EI = (const int*)d_in[1];
  const float* EW = (const float*)d_in[2];
  const float* W1 = (const float*)d_in[3];
  const float* b1 = (const float*)d_in[4];
  const float* W2 = (const float*)d_in[5];
  const float* b2 = (const float*)d_in[6];
  float* out = (float*)d_out;

  char* p = (char*)d_ws;
  auto take = [&](size_t bytes) {
    char* r = p;
    p += (bytes + 511) & ~(size_t)511;
    return r;
  };
  unsigned short* W1t   = (unsigned short*)take((size_t)N_HID * N_FEAT * 2);
  unsigned short* W2t   = (unsigned short*)take((size_t)48 * N_HID * 2);
  int*            cnt   = (int*)take((size_t)N_NODES * 4);
  int*            rp    = (int*)take((size_t)(N_NODES + 1) * 4);
  int*            bsum  = (int*)take((size_t)128 * 4);
  int*            boffs = (int*)take((size_t)128 * 4);
  int*            rank  = (int*)take((size_t)N_EDGES * 4);
  unsigned int*   cwp   = (unsigned int*)take((size_t)N_EDGES * 4);
  unsigned short* H1    = (unsigned short*)take((size_t)N_NODES * N_HID * 2);
  unsigned short* H1r   = (unsigned short*)take((size_t)N_NODES * N_HID * 2);
  float*          H2    = (float*)take((size_t)N_NODES * H2S * 4);

  const int NB_SCAN = (N_NODES + 1023) / 1024;

  k_zero<<<NB_SCAN, 1024, 0, stream>>>(cnt);
  k_pre<<<HIST_BLOCKS + W1T_BLOCKS + W2T_BLOCKS, 256, 0, stream>>>(W1, W2, EI, W1t, W2t, cnt, rank);
  k_scan_a<<<NB_SCAN, 1024, 0, stream>>>(cnt, rp, bsum);
  k_scan_b<<<1, 128, 0, stream>>>(bsum, boffs, rp);
  k_scan_c<<<(N_NODES + 255) / 256, 256, 0, stream>>>(rp, boffs);
  k_scatter<<<(N_EDGES + 2047) / 2048, 512, 0, stream>>>(EI, EW, rank, rp, cwp);
  k_gemm1<<<250, 1024, 0, stream>>>(X, W1t, b1, H1);
  k_spmm1<<<(N_NODES + 3) / 4, 256, 0, stream>>>(rp, cwp, H1, H1r);
  k_gemm2<<<(N_NODES + 127) / 128, 256, 0, stream>>>(H1r, W2t, b2, H2);
  k_spmm2_lsm<<<(N_NODES + 3) / 4, 256, 0, stream>>>(rp, cwp, H2, out);
}

// Round 12
// 441.258 us; speedup vs baseline: 1.0801x; 1.0711x over previous
//
#include <hip/hip_runtime.h>
#include <stdint.h>

#define N_NODES 100000
#define N_EDGES 1600000
#define N_FEAT 512
#define N_HID 256
#define N_CLASS 40
#define H2S 48                      // padded H2 row stride (floats)

typedef float f32x4 __attribute__((ext_vector_type(4)));
typedef __bf16 bf16x8 __attribute__((ext_vector_type(8)));
typedef unsigned short u16x4 __attribute__((ext_vector_type(4)));
typedef unsigned short u16x8 __attribute__((ext_vector_type(8)));

__device__ __forceinline__ unsigned short f2bf(float f) {
  unsigned int u = __float_as_uint(f);
  unsigned int r = (u + 0x7FFFu + ((u >> 16) & 1u)) >> 16;
  return (unsigned short)r;
}
__device__ __forceinline__ float bf2f(unsigned short s) {
  return __uint_as_float(((unsigned int)s) << 16);
}
// packed edge: bits [31:17] = bf16(w) sans sign, [16:0] = col
__device__ __forceinline__ float pk_w(unsigned int p) {
  return __uint_as_float((p >> 17) << 16);
}
__device__ __forceinline__ int pk_c(unsigned int p) { return (int)(p & 0x1FFFFu); }

// ---------------- zero cnt ----------------
__global__ __launch_bounds__(1024) void k_zero(int* __restrict__ cnt) {
  int i = blockIdx.x * 1024 + threadIdx.x;
  if (i < N_NODES) cnt[i] = 0;
}

// ---------------- preamble: W1 transpose+cvt | W2 transpose+cvt | hist(+rank) ------
#define HIST_BLOCKS 1563
#define W1T_BLOCKS  512
#define W2T_BLOCKS  48
__global__ __launch_bounds__(256) void k_pre(const float* __restrict__ W1,
                                             const float* __restrict__ W2,
                                             const int* __restrict__ ei,
                                             unsigned short* __restrict__ W1t,
                                             unsigned short* __restrict__ W2t,
                                             int* __restrict__ cnt,
                                             int* __restrict__ rank) {
  const int bid = blockIdx.x, tid = threadIdx.x;
  if (bid < HIST_BLOCKS) {
    #pragma unroll
    for (int k = 0; k < 4; ++k) {
      int e = bid * 1024 + k * 256 + tid;
      if (e < N_EDGES) rank[e] = atomicAdd(&cnt[ei[e]], 1);
    }
  } else if (bid < HIST_BLOCKS + W1T_BLOCKS) {
    int gid = (bid - HIST_BLOCKS) * 256 + tid;       // W1t[n][k]
    int n = gid >> 9, k = gid & 511;
    W1t[gid] = f2bf(W1[(long)k * N_HID + n]);
  } else {
    int gid = (bid - HIST_BLOCKS - W1T_BLOCKS) * 256 + tid;  // W2t[n][k], n pad 48
    int n = gid >> 8, k = gid & 255;
    W2t[gid] = (n < N_CLASS) ? f2bf(W2[(long)k * N_CLASS + n]) : (unsigned short)0;
  }
}

// ---------------- scan (3 passes) ----------------
__global__ __launch_bounds__(1024) void k_scan_a(const int* __restrict__ cnt,
                                                 int* __restrict__ rp,
                                                 int* __restrict__ bsum) {
  __shared__ int sm[1024];
  const int tid = threadIdx.x;
  const int i = blockIdx.x * 1024 + tid;
  int v = (i < N_NODES) ? cnt[i] : 0;
  sm[tid] = v;
  __syncthreads();
  #pragma unroll
  for (int d = 1; d < 1024; d <<= 1) {
    int t = (tid >= d) ? sm[tid - d] : 0;
    __syncthreads();
    sm[tid] += t;
    __syncthreads();
  }
  if (i < N_NODES) rp[i] = sm[tid] - v;
  if (tid == 1023) bsum[blockIdx.x] = sm[1023];
}

__global__ __launch_bounds__(128) void k_scan_b(const int* __restrict__ bsum,
                                                int* __restrict__ boffs,
                                                int* __restrict__ rp) {
  __shared__ int sm[128];
  const int tid = threadIdx.x;
  const int nb = (N_NODES + 1023) >> 10;
  int v = (tid < nb) ? bsum[tid] : 0;
  sm[tid] = v;
  __syncthreads();
  #pragma unroll
  for (int d = 1; d < 128; d <<= 1) {
    int t = (tid >= d) ? sm[tid - d] : 0;
    __syncthreads();
    sm[tid] += t;
    __syncthreads();
  }
  boffs[tid] = sm[tid] - v;
  if (tid == 127) rp[N_NODES] = sm[127];
}

__global__ void k_scan_c(int* __restrict__ rp, const int* __restrict__ boffs) {
  int i = blockIdx.x * 256 + threadIdx.x;
  if (i >= N_NODES) return;
  rp[i] += boffs[i >> 10];
}

// ---------------- scatter: packed 4B records, no atomics ----------------
__global__ __launch_bounds__(512) void k_scatter(const int* __restrict__ ei,
                                                 const float* __restrict__ ew,
                                                 const int* __restrict__ rank,
                                                 const int* __restrict__ rp,
                                                 unsigned int* __restrict__ cwp) {
  const int t = threadIdx.x;
  #pragma unroll
  for (int k = 0; k < 4; ++k) {
    int e = blockIdx.x * 2048 + k * 512 + t;
    if (e < N_EDGES) {
      int r = ei[e];
      int pos = rp[r] + rank[e];
      unsigned int w15 = (unsigned int)f2bf(ew[e]);      // sign always 0
      cwp[pos] = (w15 << 17) | (unsigned int)ei[N_EDGES + e];
    }
  }
}

// ---------------- GEMM1 v3: X read ONCE; B K-halved in LDS; A-half reg-cached -------
// 391 blocks x 256 rows x full N=256. 16 waves; wave owns 16 rows, all 256 cols.
// Per K-half (256 k): stage Bs[256 cols][256 k] (128 KB, slot-XOR swizzle), then each
// lane caches its A row-half in regs (8 x bf16x8) and runs 16 col-tiles x 8 k-steps.
#define G1_BLOCKS 391               // ceil(100000/256)
__global__ __launch_bounds__(1024) void k_gemm1(const float* __restrict__ X,
                                                const unsigned short* __restrict__ W1t,
                                                const float* __restrict__ b1,
                                                unsigned short* __restrict__ H1) {
  __shared__ __align__(16) unsigned short Bs[256 * 256];   // 128 KB
  const int t = threadIdx.x;
  const long rb = (long)blockIdx.x * 256;
  const int lane = t & 63;
  const int wid = t >> 6;                  // 0..15: wave's 16-row chunk
  const int lr = lane & 15;
  const int lkg = lane >> 4;               // 0..3

  long myrow = rb + wid * 16 + lr;
  if (myrow >= N_NODES) myrow = N_NODES - 1;   // clamp (stores guarded)
  const float* xrow = X + myrow * N_FEAT;

  f32x4 acc[16] = {};

  #pragma unroll 1
  for (int kc = 0; kc < 2; ++kc) {
    __syncthreads();                       // prev half's reads complete
    {
      const int col = t >> 2;              // 0..255
      const int sg = (t & 3) * 8;          // 8 slots of 8 shorts each
      const unsigned short* src = W1t + (long)col * N_FEAT + kc * 256;
      #pragma unroll
      for (int j = 0; j < 8; ++j) {
        int slot = sg + j;                 // 0..31
        int ps = slot ^ (col & 7);
        *(u16x8*)&Bs[col * 256 + ps * 8] = *(const u16x8*)(src + slot * 8);
      }
    }
    __syncthreads();

    // A row-half into registers (X read exactly once, non-temporal)
    bf16x8 av[8];
    #pragma unroll
    for (int ks = 0; ks < 8; ++ks) {
      const float* xp = xrow + kc * 256 + ks * 32 + lkg * 8;
      f32x4 xa = __builtin_nontemporal_load((const f32x4*)xp);
      f32x4 xb = __builtin_nontemporal_load((const f32x4*)(xp + 4));
      bf16x8 v;
      v[0] = (__bf16)xa[0]; v[1] = (__bf16)xa[1];
      v[2] = (__bf16)xa[2]; v[3] = (__bf16)xa[3];
      v[4] = (__bf16)xb[0]; v[5] = (__bf16)xb[1];
      v[6] = (__bf16)xb[2]; v[7] = (__bf16)xb[3];
      av[ks] = v;
    }

    #pragma unroll
    for (int ks = 0; ks < 8; ++ks) {
      const int slot = ks * 4 + lkg;
      const int ps = slot ^ (lr & 7);
      #pragma unroll
      for (int nt = 0; nt < 16; ++nt) {
        bf16x8 bv = *(const bf16x8*)&Bs[(nt * 16 + lr) * 256 + ps * 8];
        acc[nt] = __builtin_amdgcn_mfma_f32_16x16x32_bf16(av[ks], bv, acc[nt], 0, 0, 0);
      }
    }
  }

  #pragma unroll
  for (int nt = 0; nt < 16; ++nt) {
    int colg = nt * 16 + lr;
    float bias = b1[colg];
    #pragma unroll
    for (int i = 0; i < 4; ++i) {
      long row = rb + wid * 16 + lkg * 4 + i;
      if (row < N_NODES) H1[row * N_HID + colg] = f2bf(acc[nt][i] + bias);
    }
  }
}

// ---------------- SPMM1 + relu: H1r = bf16(relu(A @ H1)), 8-deep gather ----------
__global__ __launch_bounds__(256) void k_spmm1(const int* __restrict__ row_ptr,
                                               const unsigned int* __restrict__ cwp,
                                               const unsigned short* __restrict__ H1,
                                               unsigned short* __restrict__ H1r) {
  int r = blockIdx.x * 4 + (threadIdx.x >> 6);
  int lane = threadIdx.x & 63;
  if (r >= N_NODES) return;
  int s = row_ptr[r], e = row_ptr[r + 1];
  float a0 = 0.f, a1 = 0.f, a2 = 0.f, a3 = 0.f;
  const unsigned short* Hb = H1 + lane * 4;
  int i = s;
  for (; i + 8 <= e; i += 8) {
    uint4 q0 = *(const uint4*)(cwp + i);
    uint4 q1 = *(const uint4*)(cwp + i + 4);
    unsigned int cc[8] = {q0.x, q0.y, q0.z, q0.w, q1.x, q1.y, q1.z, q1.w};
    u16x4 h[8];
    #pragma unroll
    for (int j = 0; j < 8; ++j)
      h[j] = *(const u16x4*)(Hb + (long)pk_c(cc[j]) * N_HID);
    #pragma unroll
    for (int j = 0; j < 8; ++j) {
      float w = pk_w(cc[j]);
      a0 += w * bf2f(h[j][0]);
      a1 += w * bf2f(h[j][1]);
      a2 += w * bf2f(h[j][2]);
      a3 += w * bf2f(h[j][3]);
    }
  }
  for (; i < e; ++i) {
    unsigned int p = cwp[i];
    float w = pk_w(p);
    u16x4 hv = *(const u16x4*)(Hb + (long)pk_c(p) * N_HID);
    a0 += w * bf2f(hv[0]);
    a1 += w * bf2f(hv[1]);
    a2 += w * bf2f(hv[2]);
    a3 += w * bf2f(hv[3]);
  }
  u16x4 o;
  o[0] = f2bf(fmaxf(a0, 0.f));
  o[1] = f2bf(fmaxf(a1, 0.f));
  o[2] = f2bf(fmaxf(a2, 0.f));
  o[3] = f2bf(fmaxf(a3, 0.f));
  *(u16x4*)(H1r + (long)r * N_HID + lane * 4) = o;
}

// ---------------- GEMM2 direct-from-global: H2[.][48] = H1r @ W2 + b2 -------------
__global__ __launch_bounds__(256) void k_gemm2(const unsigned short* __restrict__ H1r,
                                               const unsigned short* __restrict__ W2t,
                                               const float* __restrict__ b2,
                                               float* __restrict__ H2) {
  const int t = threadIdx.x;
  const int lane = t & 63;
  const int wid = t >> 6;
  const long m0 = (long)blockIdx.x * 128;
  const int lr = lane & 15;
  const int lk = (lane >> 4) * 8;

  const unsigned short* Ab[2];
  #pragma unroll
  for (int mt = 0; mt < 2; ++mt) {
    long r = m0 + wid * 32 + mt * 16 + lr;
    if (r >= N_NODES) r = N_NODES - 1;
    Ab[mt] = H1r + r * N_HID + lk;
  }
  const unsigned short* Bb[3];
  #pragma unroll
  for (int nt = 0; nt < 3; ++nt)
    Bb[nt] = W2t + (long)(nt * 16 + lr) * N_HID + lk;

  f32x4 acc[2][3] = {};
  #pragma unroll
  for (int k0 = 0; k0 < N_HID; k0 += 32) {
    bf16x8 av[2], bvv[3];
    #pragma unroll
    for (int mt = 0; mt < 2; ++mt) av[mt] = *(const bf16x8*)(Ab[mt] + k0);
    #pragma unroll
    for (int nt = 0; nt < 3; ++nt) bvv[nt] = *(const bf16x8*)(Bb[nt] + k0);
    #pragma unroll
    for (int mt = 0; mt < 2; ++mt)
      #pragma unroll
      for (int nt = 0; nt < 3; ++nt)
        acc[mt][nt] = __builtin_amdgcn_mfma_f32_16x16x32_bf16(av[mt], bvv[nt], acc[mt][nt], 0, 0, 0);
  }

  #pragma unroll
  for (int nt = 0; nt < 3; ++nt) {
    int col = nt * 16 + lr;
    if (col < N_CLASS) {
      float bias = b2[col];
      #pragma unroll
      for (int mt = 0; mt < 2; ++mt) {
        #pragma unroll
        for (int i = 0; i < 4; ++i) {
          long row = m0 + wid * 32 + mt * 16 + (lane >> 4) * 4 + i;
          if (row < N_NODES) H2[row * H2S + col] = acc[mt][nt][i] + bias;
        }
      }
    }
  }
}

// ---------------- SPMM2 + log_softmax fused, 8-deep, packed edges ----------------
__global__ __launch_bounds__(256) void k_spmm2_lsm(const int* __restrict__ row_ptr,
                                                   const unsigned int* __restrict__ cwp,
                                                   const float* __restrict__ H2,
                                                   float* __restrict__ out) {
  int r = blockIdx.x * 4 + (threadIdx.x >> 6);
  int lane = threadIdx.x & 63;
  if (r >= N_NODES) return;
  int s = row_ptr[r], e = row_ptr[r + 1];
  float acc = 0.f;
  const bool act = lane < N_CLASS;
  int i = s;
  for (; i + 8 <= e; i += 8) {
    uint4 q0 = *(const uint4*)(cwp + i);
    uint4 q1 = *(const uint4*)(cwp + i + 4);
    unsigned int cc[8] = {q0.x, q0.y, q0.z, q0.w, q1.x, q1.y, q1.z, q1.w};
    float h[8];
    #pragma unroll
    for (int j = 0; j < 8; ++j)
      h[j] = act ? H2[(long)pk_c(cc[j]) * H2S + lane] : 0.f;
    #pragma unroll
    for (int j = 0; j < 8; ++j) acc += pk_w(cc[j]) * h[j];
  }
  for (; i < e; ++i) {
    unsigned int p = cwp[i];
    if (act) acc += pk_w(p) * H2[(long)pk_c(p) * H2S + lane];
  }
  float v = act ? acc : -INFINITY;
  float m = v;
  #pragma unroll
  for (int d = 32; d > 0; d >>= 1) m = fmaxf(m, __shfl_xor(m, d));
  float ex = act ? __expf(v - m) : 0.f;
  float ssum = ex;
  #pragma unroll
  for (int d = 32; d > 0; d >>= 1) ssum += __shfl_xor(ssum, d);
  float ls = __logf(ssum);
  if (act) out[(long)r * N_CLASS + lane] = v - m - ls;
}

extern "C" void kernel_launch(void* const* d_in, const int* in_sizes, int n_in,
                              void* d_out, int out_size, void* d_ws, size_t ws_size,
                              hipStream_t stream) {
  (void)in_sizes; (void)n_in; (void)out_size; (void)ws_size;
  const float* X  = (const float*)d_in[0];
  const int*   EI = (const int*)d_in[1];
  const float* EW = (const float*)d_in[2];
  const float* W1 = (const float*)d_in[3];
  const float* b1 = (const float*)d_in[4];
  const float* W2 = (const float*)d_in[5];
  const float* b2 = (const float*)d_in[6];
  float* out = (float*)d_out;

  char* p = (char*)d_ws;
  auto take = [&](size_t bytes) {
    char* r = p;
    p += (bytes + 511) & ~(size_t)511;
    return r;
  };
  unsigned short* W1t   = (unsigned short*)take((size_t)N_HID * N_FEAT * 2);
  unsigned short* W2t   = (unsigned short*)take((size_t)48 * N_HID * 2);
  int*            cnt   = (int*)take((size_t)N_NODES * 4);
  int*            rp    = (int*)take((size_t)(N_NODES + 1) * 4);
  int*            bsum  = (int*)take((size_t)128 * 4);
  int*            boffs = (int*)take((size_t)128 * 4);
  int*            rank  = (int*)take((size_t)N_EDGES * 4);
  unsigned int*   cwp   = (unsigned int*)take((size_t)N_EDGES * 4);
  unsigned short* H1    = (unsigned short*)take((size_t)N_NODES * N_HID * 2);
  unsigned short* H1r   = (unsigned short*)take((size_t)N_NODES * N_HID * 2);
  float*          H2    = (float*)take((size_t)N_NODES * H2S * 4);

  const int NB_SCAN = (N_NODES + 1023) / 1024;

  k_zero<<<NB_SCAN, 1024, 0, stream>>>(cnt);
  k_pre<<<HIST_BLOCKS + W1T_BLOCKS + W2T_BLOCKS, 256, 0, stream>>>(W1, W2, EI, W1t, W2t, cnt, rank);
  k_scan_a<<<NB_SCAN, 1024, 0, stream>>>(cnt, rp, bsum);
  k_scan_b<<<1, 128, 0, stream>>>(bsum, boffs, rp);
  k_scan_c<<<(N_NODES + 255) / 256, 256, 0, stream>>>(rp, boffs);
  k_scatter<<<(N_EDGES + 2047) / 2048, 512, 0, stream>>>(EI, EW, rank, rp, cwp);
  k_gemm1<<<G1_BLOCKS, 1024, 0, stream>>>(X, W1t, b1, H1);
  k_spmm1<<<(N_NODES + 3) / 4, 256, 0, stream>>>(rp, cwp, H1, H1r);
  k_gemm2<<<(N_NODES + 127) / 128, 256, 0, stream>>>(H1r, W2t, b2, H2);
  k_spmm2_lsm<<<(N_NODES + 3) / 4, 256, 0, stream>>>(rp, cwp, H2, out);
}